// Round 2
// baseline (318.892 us; speedup 1.0000x reference)
//
#include <hip/hip_runtime.h>
#include <hip/hip_bf16.h>

#define NSEQ 4096
#define DHEAD 128
#define NB 4
#define PSTR 72   // P row stride (bf16 elems): (lc*144+lg*16) mod 128 uniform -> conflict-free b128

typedef __attribute__((ext_vector_type(8))) short bf16x8;
typedef __attribute__((ext_vector_type(4))) short bf16x4;
typedef __attribute__((ext_vector_type(4))) float f32x4;

__device__ __forceinline__ unsigned short f2bf(float f) {
  return __builtin_bit_cast(unsigned short, __float2bfloat16(f));
}

template <int CTRL>
__device__ __forceinline__ float dpp_rot(float x) {
  int v = __builtin_amdgcn_update_dpp(0, __builtin_bit_cast(int, x), CTRL, 0xF, 0xF, false);
  return __builtin_bit_cast(float, v);
}

// ---------------- pre-pass: fp32 -> bf16 row-major (Xb) + transposed (Xt) ----------------
__global__ __launch_bounds__(256) void prep_kernel(const float* __restrict__ S,
                                                   const float* __restrict__ G,
                                                   unsigned short* __restrict__ ws) {
  const int tens = blockIdx.z, b = blockIdx.y, n0 = blockIdx.x * 64;
  const size_t AR = (size_t)NB * NSEQ * DHEAD;
  const float* X = (tens ? G : S) + (size_t)b * NSEQ * DHEAD;
  unsigned short* Xb = ws + (size_t)tens * AR + (size_t)b * NSEQ * DHEAD;
  unsigned short* Xt = ws + (size_t)(2 + tens) * AR + (size_t)b * NSEQ * DHEAD;
  __shared__ unsigned short tl[128][72];
  const int tid = threadIdx.x;
  #pragma unroll
  for (int i = 0; i < 8; ++i) {
    int idx = i * 256 + tid;
    int nl = idx >> 5, d0 = (idx & 31) * 4;
    float4 v = *(const float4*)(X + (size_t)(n0 + nl) * DHEAD + d0);
    unsigned short c0 = f2bf(v.x), c1 = f2bf(v.y), c2 = f2bf(v.z), c3 = f2bf(v.w);
    bf16x4 r = {(short)c0, (short)c1, (short)c2, (short)c3};
    *(bf16x4*)(Xb + (size_t)(n0 + nl) * DHEAD + d0) = r;
    tl[d0][nl] = c0; tl[d0 + 1][nl] = c1; tl[d0 + 2][nl] = c2; tl[d0 + 3][nl] = c3;
  }
  __syncthreads();
  #pragma unroll
  for (int j = 0; j < 8; ++j) {
    int idx = j * 256 + tid;
    int d = idx >> 4, nl4 = (idx & 15) * 4;
    bf16x4 r = {(short)tl[d][nl4], (short)tl[d][nl4 + 1], (short)tl[d][nl4 + 2], (short)tl[d][nl4 + 3]};
    *(bf16x4*)(Xt + (size_t)d * NSEQ + n0 + nl4) = r;
  }
}

// ---------------- main: both passes for one 64-row block; no-max softmax ----------------
__global__ __launch_bounds__(512, 2)
void xattn2_kernel(const float* __restrict__ S, const float* __restrict__ G,
                   const unsigned short* __restrict__ ws, float* __restrict__ out) {
  const int qblk = blockIdx.x, b = blockIdx.y;
  const int tid = threadIdx.x, w = tid >> 6, l = tid & 63, lg = l >> 4, lc = l & 15;
  const int pass = w >> 2, kvh = (w >> 1) & 1, qh = w & 1;
  const size_t AR = (size_t)NB * NSEQ * DHEAD;
  const float* Qf = (pass ? G : S) + (size_t)b * NSEQ * DHEAD;
  const unsigned short* Kb = ws + (pass ? 0 : AR) + (size_t)b * NSEQ * DHEAD;        // pass0: Gb, pass1: Sb
  const unsigned short* Vt = ws + (pass ? 2 * AR : 3 * AR) + (size_t)b * NSEQ * DHEAD; // pass0: Gt, pass1: St

  __shared__ __align__(16) char smem[66560];
  unsigned short* pw = (unsigned short*)smem + w * (32 * PSTR);

  // fold 1/sqrt(D)*log2(e) into Q -> softmax in exp2 domain, no max subtraction
  const float qsc = 0.08838834764831845f * 1.44269504088896341f;
  bf16x8 qf[2][4];
  #pragma unroll
  for (int rg = 0; rg < 2; ++rg) {
    const float* qs = Qf + (size_t)(qblk * 64 + qh * 32 + rg * 16 + lc) * DHEAD + lg * 8;
    #pragma unroll
    for (int kc = 0; kc < 4; ++kc) {
      float4 a = *(const float4*)(qs + kc * 32);
      float4 c = *(const float4*)(qs + kc * 32 + 4);
      bf16x8 q;
      q[0] = (short)f2bf(a.x * qsc); q[1] = (short)f2bf(a.y * qsc);
      q[2] = (short)f2bf(a.z * qsc); q[3] = (short)f2bf(a.w * qsc);
      q[4] = (short)f2bf(c.x * qsc); q[5] = (short)f2bf(c.y * qsc);
      q[6] = (short)f2bf(c.z * qsc); q[7] = (short)f2bf(c.w * qsc);
      qf[rg][kc] = q;
    }
  }

  f32x4 oacc[2][8];
  #pragma unroll
  for (int rg = 0; rg < 2; ++rg)
    #pragma unroll
    for (int i = 0; i < 8; ++i) oacc[rg][i] = {0.f, 0.f, 0.f, 0.f};
  float lrow[2][4] = {{0.f, 0.f, 0.f, 0.f}, {0.f, 0.f, 0.f, 0.f}};

  for (int tt = 0; tt < 32; ++tt) {
    const int t = kvh * 32 + tt;
    const unsigned short* Kt = Kb + (size_t)t * 64 * DHEAD;
    const unsigned short* Vtt = Vt + t * 64;

    // ---- QK^T ----
    f32x4 sim[2][4];
    #pragma unroll
    for (int cc = 0; cc < 4; ++cc) {
      bf16x8 kf[4];
      #pragma unroll
      for (int kc = 0; kc < 4; ++kc)
        kf[kc] = *(const bf16x8*)(Kt + (size_t)(cc * 16 + lc) * DHEAD + kc * 32 + lg * 8);
      #pragma unroll
      for (int rg = 0; rg < 2; ++rg) {
        f32x4 acc = {0.f, 0.f, 0.f, 0.f};
        #pragma unroll
        for (int kc = 0; kc < 4; ++kc)
          acc = __builtin_amdgcn_mfma_f32_16x16x32_bf16(qf[rg][kc], kf[kc], acc, 0, 0, 0);
        sim[rg][cc] = acc;
      }
    }

    // ---- no-max softmax accumulation ----
    #pragma unroll
    for (int rg = 0; rg < 2; ++rg) {
      #pragma unroll
      for (int r = 0; r < 4; ++r) {
        float p0 = exp2f(sim[rg][0][r]);
        float p1 = exp2f(sim[rg][1][r]);
        float p2 = exp2f(sim[rg][2][r]);
        float p3 = exp2f(sim[rg][3][r]);
        sim[rg][0][r] = p0; sim[rg][1][r] = p1; sim[rg][2][r] = p2; sim[rg][3][r] = p3;
        float ts = (p0 + p1) + (p2 + p3);
        ts += dpp_rot<0x121>(ts);
        ts += dpp_rot<0x122>(ts);
        ts += dpp_rot<0x124>(ts);
        ts += dpp_rot<0x128>(ts);
        lrow[rg][r] += ts;
      }
    }

    // ---- P (C-layout) -> per-wave LDS (A-layout source) ----
    #pragma unroll
    for (int rg = 0; rg < 2; ++rg)
      #pragma unroll
      for (int cc = 0; cc < 4; ++cc)
        #pragma unroll
        for (int r = 0; r < 4; ++r)
          pw[(rg * 16 + lg * 4 + r) * PSTR + cc * 16 + lc] = f2bf(sim[rg][cc][r]);

    // ---- PV: O += P · V  (V fragments straight from L2-cached transposed copy) ----
    #pragma unroll
    for (int kc2 = 0; kc2 < 2; ++kc2) {
      bf16x8 pf0 = *(const bf16x8*)&pw[(lc) * PSTR + kc2 * 32 + lg * 8];
      bf16x8 pf1 = *(const bf16x8*)&pw[(16 + lc) * PSTR + kc2 * 32 + lg * 8];
      #pragma unroll
      for (int dc = 0; dc < 8; ++dc) {
        bf16x8 vf = *(const bf16x8*)(Vtt + (size_t)(dc * 16 + lc) * NSEQ + kc2 * 32 + lg * 8);
        oacc[0][dc] = __builtin_amdgcn_mfma_f32_16x16x32_bf16(pf0, vf, oacc[0][dc], 0, 0, 0);
        oacc[1][dc] = __builtin_amdgcn_mfma_f32_16x16x32_bf16(pf1, vf, oacc[1][dc], 0, 0, 0);
      }
    }
  }

  // ---- merge kv-halves + normalize + write (no atomics, no memset) ----
  __syncthreads();
  float* mb = (float*)smem;        // [2][64][129]
  float* lb = mb + 2 * 64 * 129;   // [2][64]
  if (kvh == 1) {
    #pragma unroll
    for (int rg = 0; rg < 2; ++rg) {
      #pragma unroll
      for (int dc = 0; dc < 8; ++dc)
        #pragma unroll
        for (int r = 0; r < 4; ++r)
          mb[pass * 8256 + (qh * 32 + rg * 16 + lg * 4 + r) * 129 + dc * 16 + lc] = oacc[rg][dc][r];
      if (lc == 0) {
        #pragma unroll
        for (int r = 0; r < 4; ++r)
          lb[pass * 64 + qh * 32 + rg * 16 + lg * 4 + r] = lrow[rg][r];
      }
    }
  }
  __syncthreads();
  if (kvh == 0) {
    #pragma unroll
    for (int rg = 0; rg < 2; ++rg) {
      #pragma unroll
      for (int dc = 0; dc < 8; ++dc)
        #pragma unroll
        for (int r = 0; r < 4; ++r)
          mb[pass * 8256 + (qh * 32 + rg * 16 + lg * 4 + r) * 129 + dc * 16 + lc] += oacc[rg][dc][r];
      if (lc == 0) {
        #pragma unroll
        for (int r = 0; r < 4; ++r)
          lb[pass * 64 + qh * 32 + rg * 16 + lg * 4 + r] += lrow[rg][r];
      }
    }
  }
  __syncthreads();
  #pragma unroll
  for (int i = 0; i < 16; ++i) {
    int idx = i * 512 + tid;
    int row = idx >> 7, d = idx & 127;
    float o0 = mb[row * 129 + d] / lb[row];
    float o1 = mb[8256 + row * 129 + d] / lb[64 + row];
    out[((size_t)b * NSEQ + qblk * 64 + row) * DHEAD + d] = 0.5f * (o0 + o1);
  }
}

extern "C" void kernel_launch(void* const* d_in, const int* in_sizes, int n_in,
                              void* d_out, int out_size, void* d_ws, size_t ws_size,
                              hipStream_t stream) {
  const float* S = (const float*)d_in[0];
  const float* G = (const float*)d_in[1];
  unsigned short* ws = (unsigned short*)d_ws;
  float* outp = (float*)d_out;
  prep_kernel<<<dim3(64, 4, 2), 256, 0, stream>>>(S, G, ws);
  xattn2_kernel<<<dim3(64, 4), 512, 0, stream>>>(S, G, ws, outp);
}

// Round 3
// 170.248 us; speedup vs baseline: 1.8731x; 1.8731x over previous
//
#include <hip/hip_runtime.h>
#include <hip/hip_bf16.h>

#define NSEQ 4096
#define DHEAD 128
#define NB 4

typedef __attribute__((ext_vector_type(8))) short bf16x8;
typedef __attribute__((ext_vector_type(4))) float f32x4;

// ws layout (bf16 element offsets)
#define KF_S 0u
#define KF_G 2097152u
#define VF_S 4194304u
#define VF_G 6553600u
#define OBUF_BYTE 17825792u   // float region: [pass 2][b 4][4096][128]

typedef __attribute__((address_space(3))) void lds_void;
typedef const __attribute__((address_space(1))) void g_void;
#define GLOAD(gp, lp) __builtin_amdgcn_global_load_lds((g_void*)(gp), (lds_void*)(lp), 16, 0, 0)

__device__ __forceinline__ unsigned short f2bf(float f) {
  return __builtin_bit_cast(unsigned short, __float2bfloat16(f));
}

// ---------- prep: fp32 -> bf16 fragment-major K tiles + V^T tiles (with ones-block) ----------
__global__ __launch_bounds__(256) void prep_kernel(const float* __restrict__ S,
                                                   const float* __restrict__ G,
                                                   unsigned short* __restrict__ ws) {
  const int t = blockIdx.x, b = blockIdx.y, tens = blockIdx.z;   // t: 64-row supertile
  const float* X = (tens ? G : S) + ((size_t)b * NSEQ + t * 64) * DHEAD;
  unsigned short* Kf = ws + (tens ? KF_G : KF_S) + (size_t)b * 524288 + (size_t)t * 8192;
  unsigned short* Vf = ws + (tens ? VF_G : VF_S) + (size_t)b * 589824 + (size_t)t * 9216;
  __shared__ unsigned short tl[64 * 138];
  const int tid = threadIdx.x;
  #pragma unroll
  for (int i = 0; i < 4; ++i) {
    int idx = i * 256 + tid;                       // 1024 fragment-units of 8 elems
    int tt = idx >> 9, inst = (idx >> 6) & 7, lane = idx & 63;
    int cc = inst >> 2, kc = inst & 3, lg = lane >> 4, lc = lane & 15;
    int row = tt * 32 + cc * 16 + lc, col = kc * 32 + lg * 8;
    float4 a = *(const float4*)(X + (size_t)row * DHEAD + col);
    float4 c = *(const float4*)(X + (size_t)row * DHEAD + col + 4);
    unsigned short e[8] = {f2bf(a.x), f2bf(a.y), f2bf(a.z), f2bf(a.w),
                           f2bf(c.x), f2bf(c.y), f2bf(c.z), f2bf(c.w)};
    bf16x8 v;
    #pragma unroll
    for (int j = 0; j < 8; ++j) v[j] = (short)e[j];
    *(bf16x8*)(Kf + (size_t)idx * 8) = v;
    int base = row * 138 + col;
    #pragma unroll
    for (int k = 0; k < 4; ++k)
      *(unsigned int*)&tl[base + k * 2] = (unsigned)e[2 * k] | ((unsigned)e[2 * k + 1] << 16);
  }
  __syncthreads();
  #pragma unroll
  for (int j = 0; j < 5; ++j) {
    int idx = j * 256 + tid;                       // 1152 units: 2 tiles x 9 dc x 64 lanes
    if (idx < 1152) {
      int tt = idx >= 576, rem = idx - tt * 576;
      int dc = rem >> 6, lane = rem & 63, lg = lane >> 4, lc = lane & 15;
      bf16x8 v;
      if (dc == 8) {
        #pragma unroll
        for (int k = 0; k < 8; ++k) v[k] = (short)0x3F80;   // ones row-block -> l via MFMA
      } else {
        #pragma unroll
        for (int k = 0; k < 8; ++k)
          v[k] = (short)tl[(tt * 32 + lg * 8 + k) * 138 + dc * 16 + lc];
      }
      *(bf16x8*)(Vf + (size_t)idx * 8) = v;
    }
  }
}

// ---------- main: 4 waves = qh(2) x kvh(2); K via LDS dbuf, V from L2, l via ones-MFMA ----------
__global__ __launch_bounds__(256, 2)
void xattn3_kernel(const float* __restrict__ S, const float* __restrict__ G,
                   const unsigned short* __restrict__ ws, float* __restrict__ obuf) {
  const int qblk = blockIdx.x, b = blockIdx.y, pass = blockIdx.z;
  const int tid = threadIdx.x, w = tid >> 6, lane = tid & 63;
  const int lg = lane >> 4, lc = lane & 15;
  const int qh = w & 1, kvh = w >> 1;

  const float* Qf = (pass ? G : S) + (size_t)b * NSEQ * DHEAD;
  const unsigned short* Kf = ws + (pass ? KF_S : KF_G) + (size_t)b * 524288;
  const unsigned short* Vf = ws + (pass ? VF_S : VF_G) + (size_t)b * 589824;

  __shared__ __align__(16) char smem[53248];
  // K: [0,32768) = kvh*16384 + par*8192 ; P: 32768 + w*5120 + par*2560 + rg*1280
  // merge: float mb[64][132] aliases [0,33792)

  const float qsc = 0.08838834764831845f * 1.44269504088896341f;  // 1/sqrt(128)*log2(e)
  bf16x8 qf[2][4];
  #pragma unroll
  for (int rg = 0; rg < 2; ++rg) {
    const float* qs = Qf + (size_t)(qblk * 64 + qh * 32 + rg * 16 + lc) * DHEAD + lg * 8;
    #pragma unroll
    for (int kc = 0; kc < 4; ++kc) {
      float4 a = *(const float4*)(qs + kc * 32);
      float4 c = *(const float4*)(qs + kc * 32 + 4);
      bf16x8 q;
      q[0] = (short)f2bf(a.x * qsc); q[1] = (short)f2bf(a.y * qsc);
      q[2] = (short)f2bf(a.z * qsc); q[3] = (short)f2bf(a.w * qsc);
      q[4] = (short)f2bf(c.x * qsc); q[5] = (short)f2bf(c.y * qsc);
      q[6] = (short)f2bf(c.z * qsc); q[7] = (short)f2bf(c.w * qsc);
      qf[rg][kc] = q;
    }
  }

  f32x4 oacc[2][9];
  #pragma unroll
  for (int rg = 0; rg < 2; ++rg)
    #pragma unroll
    for (int dc = 0; dc < 9; ++dc) oacc[rg][dc] = {0.f, 0.f, 0.f, 0.f};

  // per-lane global staging pointer (fragment-major => linear); wave's qh picks its 4KB half
  const char* kgp = (const char*)Kf + (size_t)(kvh * 64) * 8192 + qh * 4096 + lane * 16;
  const char* vgp = (const char*)Vf + (size_t)(kvh * 64) * 9216;
  char* klbase = smem + kvh * 16384;

  // prologue: stage tile 0 into parity 0
  {
    char* l = klbase + qh * 4096;
    GLOAD(kgp, l); GLOAD(kgp + 1024, l + 1024);
    GLOAD(kgp + 2048, l + 2048); GLOAD(kgp + 3072, l + 3072);
  }
  __syncthreads();

  for (int i = 0; i < 64; ++i) {
    const int par = i & 1;
    // V fragments for tile i: 9 coalesced 1KB reads from L1/L2 (issued early)
    const char* vt = vgp + (size_t)i * 9216 + lane * 16;
    bf16x8 vf[9];
    #pragma unroll
    for (int dc = 0; dc < 9; ++dc)
      vf[dc] = *(const bf16x8*)(vt + dc * 1024);

    // QK^T from LDS (conflict-free fragment-major reads)
    const char* kt = klbase + par * 8192 + lane * 16;
    f32x4 sim[2][2];
    #pragma unroll
    for (int cc = 0; cc < 2; ++cc) {
      f32x4 a0 = {0.f, 0.f, 0.f, 0.f}, a1 = {0.f, 0.f, 0.f, 0.f};
      #pragma unroll
      for (int kc = 0; kc < 4; ++kc) {
        bf16x8 kf = *(const bf16x8*)(kt + (cc * 4 + kc) * 1024);
        a0 = __builtin_amdgcn_mfma_f32_16x16x32_bf16(qf[0][kc], kf, a0, 0, 0, 0);
        a1 = __builtin_amdgcn_mfma_f32_16x16x32_bf16(qf[1][kc], kf, a1, 0, 0, 0);
      }
      sim[0][cc] = a0; sim[1][cc] = a1;
    }

    // stage next K tile into other parity (latency hidden under softmax+PV)
    if (i < 63) {
      const char* g = kgp + (size_t)(i + 1) * 8192;
      char* l = klbase + ((i + 1) & 1) * 8192 + qh * 4096;
      GLOAD(g, l); GLOAD(g + 1024, l + 1024);
      GLOAD(g + 2048, l + 2048); GLOAD(g + 3072, l + 3072);
    }

    // no-max softmax in exp2 domain (scale folded into Q)
    #pragma unroll
    for (int rg = 0; rg < 2; ++rg)
      #pragma unroll
      for (int cc = 0; cc < 2; ++cc)
        #pragma unroll
        for (int r = 0; r < 4; ++r)
          sim[rg][cc][r] = exp2f(sim[rg][cc][r]);

    // P -> LDS (C-layout) -> A-frag; PV with ones-block accumulating l into dc=8
    #pragma unroll
    for (int rg = 0; rg < 2; ++rg) {
      unsigned short* pw = (unsigned short*)(smem + 32768 + w * 5120 + par * 2560 + rg * 1280);
      #pragma unroll
      for (int cc = 0; cc < 2; ++cc)
        #pragma unroll
        for (int r = 0; r < 4; ++r)
          pw[(lg * 4 + r) * 40 + cc * 16 + lc] = f2bf(sim[rg][cc][r]);
      bf16x8 pf = *(const bf16x8*)((char*)pw + lc * 80 + lg * 16);
      #pragma unroll
      for (int dc = 0; dc < 9; ++dc)
        oacc[rg][dc] = __builtin_amdgcn_mfma_f32_16x16x32_bf16(pf, vf[dc], oacc[rg][dc], 0, 0, 0);
    }
    __syncthreads();
  }

  // ---- merge kv halves in LDS, normalize, coalesced store to per-pass buffer ----
  float* mb = (float*)smem;   // [64][132]
  if (kvh == 1) {
    #pragma unroll
    for (int rg = 0; rg < 2; ++rg)
      #pragma unroll
      for (int r = 0; r < 4; ++r) {
        int row = qh * 32 + rg * 16 + lg * 4 + r;
        #pragma unroll
        for (int dc = 0; dc < 8; ++dc)
          mb[row * 132 + dc * 16 + lc] = oacc[rg][dc][r];
        if (lc == 0) mb[row * 132 + 128] = oacc[rg][8][r];
      }
  }
  __syncthreads();
  if (kvh == 0) {
    #pragma unroll
    for (int rg = 0; rg < 2; ++rg)
      #pragma unroll
      for (int r = 0; r < 4; ++r) {
        int row = qh * 32 + rg * 16 + lg * 4 + r;
        float inv = 1.0f / (oacc[rg][8][r] + mb[row * 132 + 128]);
        #pragma unroll
        for (int dc = 0; dc < 8; ++dc)
          mb[row * 132 + dc * 16 + lc] = (oacc[rg][dc][r] + mb[row * 132 + dc * 16 + lc]) * inv;
      }
  }
  __syncthreads();
  float* ob = obuf + (size_t)(pass * NB + b) * 524288 + (size_t)(qblk * 64) * DHEAD;
  #pragma unroll
  for (int u = 0; u < 8; ++u) {
    int idx = u * 256 + tid;            // 2048 float4 units
    int row = idx >> 5, c4 = (idx & 31) * 4;
    *(float4*)(ob + row * 128 + c4) = *(const float4*)(mb + row * 132 + c4);
  }
}

// ---------- finalize: out = 0.5*(pass0 + pass1) ----------
__global__ __launch_bounds__(256) void finalize_kernel(const float* __restrict__ obuf,
                                                       float* __restrict__ out) {
  size_t i4 = ((size_t)blockIdx.x * 256 + threadIdx.x) * 4;
  float4 a = *(const float4*)(obuf + i4);
  float4 c = *(const float4*)(obuf + 2097152 + i4);
  float4 o = {0.5f * (a.x + c.x), 0.5f * (a.y + c.y),
              0.5f * (a.z + c.z), 0.5f * (a.w + c.w)};
  *(float4*)(out + i4) = o;
}

extern "C" void kernel_launch(void* const* d_in, const int* in_sizes, int n_in,
                              void* d_out, int out_size, void* d_ws, size_t ws_size,
                              hipStream_t stream) {
  const float* S = (const float*)d_in[0];
  const float* G = (const float*)d_in[1];
  unsigned short* ws = (unsigned short*)d_ws;
  float* obuf = (float*)((char*)d_ws + OBUF_BYTE);
  float* outp = (float*)d_out;
  prep_kernel<<<dim3(64, 4, 2), 256, 0, stream>>>(S, G, ws);
  xattn3_kernel<<<dim3(64, 4, 2), 256, 0, stream>>>(S, G, ws, obuf);
  finalize_kernel<<<2048, 256, 0, stream>>>(obuf, outp);
}

// Round 5
// 155.214 us; speedup vs baseline: 2.0545x; 1.0969x over previous
//
#include <hip/hip_runtime.h>
#include <hip/hip_bf16.h>

#define NSEQ 4096
#define DHEAD 128
#define NB 4

typedef __attribute__((ext_vector_type(8))) short bf16x8;
typedef __attribute__((ext_vector_type(16))) float f32x16;
typedef __attribute__((ext_vector_type(4))) unsigned int u32x4;

// ws byte offsets
#define KF_S 0u
#define KF_G 4194304u
#define VF_S 8388608u
#define VF_G 12582912u
#define PBUF_OFF 16777216u   // f32 [zk=4][b=4][4096][128]  (32 MB)
#define LBUF_OFF 50331648u   // f32 [zk=4][b=4][4096]       (256 KB)

typedef __attribute__((address_space(3))) void lds_void;
typedef const __attribute__((address_space(1))) void g_void;
#define GLOAD(gp, lp) __builtin_amdgcn_global_load_lds((g_void*)(gp), (lds_void*)(lp), 16, 0, 0)

__device__ __forceinline__ unsigned cvtpk(float lo, float hi) {
  unsigned r;
  asm("v_cvt_pk_bf16_f32 %0, %1, %2" : "=v"(r) : "v"(lo), "v"(hi));
  return r;
}

// v_permlane32_swap_b32 vdst, vsrc : vdst.lanes[32:63] <-> vsrc.lanes[0:31]
// (semantics fixed by the validated m214 recipe: swap(lowKV, highKV) -> both words usable)
__device__ __forceinline__ void plswap(unsigned& x, unsigned& y) {
#if defined(__has_builtin)
#if __has_builtin(__builtin_amdgcn_permlane32_swap)
  typedef unsigned u2 __attribute__((ext_vector_type(2)));
  u2 r = __builtin_amdgcn_permlane32_swap(x, y, false, false);
  x = r[0]; y = r[1];
#else
  asm("v_permlane32_swap_b32 %0, %1" : "+v"(x), "+v"(y));
#endif
#else
  asm("v_permlane32_swap_b32 %0, %1" : "+v"(x), "+v"(y));
#endif
}

// ---------- prep: fp32 -> bf16 fragment-major K frags + V^T frags ----------
__global__ __launch_bounds__(256) void prep4(const float* __restrict__ S,
                                             const float* __restrict__ G,
                                             unsigned short* __restrict__ ws) {
  const int t = blockIdx.x, b = blockIdx.y, tens = blockIdx.z;   // 32-row tile t
  const float* X = (tens ? G : S) + ((size_t)b * NSEQ + t * 32) * DHEAD;
  unsigned short* Kf = ws + ((tens ? KF_G : KF_S) >> 1) + (size_t)b * 524288 + (size_t)t * 4096;
  unsigned short* Vf = ws + ((tens ? VF_G : VF_S) >> 1) + (size_t)b * 524288 + (size_t)t * 4096;
  __shared__ unsigned short tl[32 * 132];
  const int tid = threadIdx.x;
  {
    const int c = tid >> 5, r = tid & 31;          // K frag c, kv-row r
    const float* xp = X + (size_t)r * DHEAD + c * 16;
    float4 v0 = *(const float4*)(xp);
    float4 v1 = *(const float4*)(xp + 4);
    float4 v2 = *(const float4*)(xp + 8);
    float4 v3 = *(const float4*)(xp + 12);
    unsigned w0 = cvtpk(v0.x, v0.y), w1 = cvtpk(v0.z, v0.w);
    unsigned w2 = cvtpk(v1.x, v1.y), w3 = cvtpk(v1.z, v1.w);
    unsigned w4 = cvtpk(v2.x, v2.y), w5 = cvtpk(v2.z, v2.w);
    unsigned w6 = cvtpk(v3.x, v3.y), w7 = cvtpk(v3.z, v3.w);
    u32x4 lo4 = {w0, w1, w2, w3}, hi4 = {w4, w5, w6, w7};
    *(u32x4*)(Kf + c * 512 + r * 8) = lo4;          // lane r   : d=16c+0..7
    *(u32x4*)(Kf + c * 512 + (r + 32) * 8) = hi4;   // lane r+32: d=16c+8..15
    unsigned* tp = (unsigned*)&tl[r * 132 + c * 16];
    tp[0] = w0; tp[1] = w1; tp[2] = w2; tp[3] = w3;
    tp[4] = w4; tp[5] = w5; tp[6] = w6; tp[7] = w7;
  }
  __syncthreads();
  {
    const int f = tid >> 5, dc = tid & 31;          // V frag f = c2*4+dblk
    const int c2 = f >> 2, dblk = f & 3;
    const int dcol = dblk * 32 + dc;
    unsigned a[4], bb[4];
    #pragma unroll
    for (int j2 = 0; j2 < 4; ++j2) {
      a[j2]  = (unsigned)tl[(16 * c2 + 2 * j2) * 132 + dcol] |
               ((unsigned)tl[(16 * c2 + 2 * j2 + 1) * 132 + dcol] << 16);
      bb[j2] = (unsigned)tl[(16 * c2 + 8 + 2 * j2) * 132 + dcol] |
               ((unsigned)tl[(16 * c2 + 9 + 2 * j2) * 132 + dcol] << 16);
    }
    *(u32x4*)(Vf + f * 512 + dc * 8) = *(u32x4*)a;          // lane dc   : kv=16c2+0..7
    *(u32x4*)(Vf + f * 512 + (dc + 32) * 8) = *(u32x4*)bb;  // lane dc+32: kv=16c2+8..15
  }
}

// ---------- main: 4 waves = q-subtiles; swapped QK^T, in-register P ----------
__global__ __launch_bounds__(256, 2)
void xattn4(const float* __restrict__ S, const float* __restrict__ G,
            const unsigned short* __restrict__ ws, float* __restrict__ pbuf,
            float* __restrict__ lbuf) {
  const int qks = blockIdx.x;                 // qblk*2 + ks
  const int qblk = qks >> 1, ks = qks & 1;
  const int b = blockIdx.y, z = blockIdx.z;   // z=0: Q=S,KV=G ; z=1: Q=G,KV=S
  const int tid = threadIdx.x, w = tid >> 6, l = tid & 63;
  const int hi = l >> 5, lo = l & 31;

  const float* Q = (z ? G : S) + (size_t)b * NSEQ * DHEAD;
  const unsigned short* Kf = ws + ((z ? KF_S : KF_G) >> 1) + (size_t)b * 524288;
  const unsigned short* Vf = ws + ((z ? VF_S : VF_G) >> 1) + (size_t)b * 524288;

  __shared__ __align__(16) char smem[16384];  // K dbuf 2 x 8KB

  const int q0w = qblk * 128 + w * 32;
  const float qsc = 0.08838834764831845f * 1.44269504088896341f; // 1/sqrt(D)*log2(e)

  // Q fragments (B-operand): lane l -> Q[q0w+lo][16c + hi*8 + j]
  bf16x8 qf[8];
  {
    const float* qs = Q + (size_t)(q0w + lo) * DHEAD + hi * 8;
    #pragma unroll
    for (int c = 0; c < 8; ++c) {
      float4 a = *(const float4*)(qs + c * 16);
      float4 bq = *(const float4*)(qs + c * 16 + 4);
      u32x4 u = {cvtpk(a.x * qsc, a.y * qsc), cvtpk(a.z * qsc, a.w * qsc),
                 cvtpk(bq.x * qsc, bq.y * qsc), cvtpk(bq.z * qsc, bq.w * qsc)};
      qf[c] = __builtin_bit_cast(bf16x8, u);
    }
  }

  f32x16 oac[4];
  #pragma unroll
  for (int d = 0; d < 4; ++d)
    #pragma unroll
    for (int r = 0; r < 16; ++r) oac[d][r] = 0.f;
  float lsum = 0.f;

  const int t0 = ks * 64;                     // 64 kv-tiles of 32 rows each
  const unsigned short* kg0 = Kf + (size_t)t0 * 4096 + (2 * w) * 512 + l * 8;
  char* klw = smem + (2 * w) * 1024;          // this wave's 2KB slice (uniform base)

  GLOAD(kg0, klw); GLOAD(kg0 + 512, klw + 1024);
  __syncthreads();

  for (int i = 0; i < 64; ++i) {
    const int par = i & 1;
    const char* kb = smem + par * 8192;

    // V fragments for tile i (L1/L2; shared across the 4 waves)
    const unsigned short* vt = Vf + (size_t)(t0 + i) * 4096 + l * 8;
    bf16x8 vfr[8];
    #pragma unroll
    for (int f = 0; f < 8; ++f) vfr[f] = *(const bf16x8*)(vt + f * 512);

    // swapped QK^T: sim = K x Q^T, two independent accumulation chains for ILP
    __builtin_amdgcn_s_setprio(1);
    f32x16 s0 = {}, s1 = {};
    #pragma unroll
    for (int c = 0; c < 4; ++c) {
      bf16x8 k0 = *(const bf16x8*)(kb + c * 1024 + l * 16);
      bf16x8 k1 = *(const bf16x8*)(kb + (4 + c) * 1024 + l * 16);
      s0 = __builtin_amdgcn_mfma_f32_32x32x16_bf16(k0, qf[c], s0, 0, 0, 0);
      s1 = __builtin_amdgcn_mfma_f32_32x32x16_bf16(k1, qf[4 + c], s1, 0, 0, 0);
    }
    __builtin_amdgcn_s_setprio(0);
    f32x16 sim = s0 + s1;

    // prefetch K(i+1) into other parity (in flight until end-of-iter barrier)
    if (i < 63) {
      const unsigned short* kg = Kf + (size_t)(t0 + i + 1) * 4096 + (2 * w) * 512 + l * 8;
      char* kl = smem + (par ^ 1) * 8192 + (2 * w) * 1024;
      GLOAD(kg, kl); GLOAD(kg + 512, kl + 1024);
    }

    // p = exp2(sim); lane-local partial of softmax denominator
    float p[16];
    #pragma unroll
    for (int r = 0; r < 16; ++r) p[r] = __builtin_amdgcn_exp2f(sim[r]);
    lsum += ((((p[0] + p[1]) + (p[2] + p[3])) + ((p[4] + p[5]) + (p[6] + p[7]))) +
             (((p[8] + p[9]) + (p[10] + p[11])) + ((p[12] + p[13]) + (p[14] + p[15]))));

    // pack to bf16 + permlane32_swap -> PV A-fragments (no LDS, no barrier)
    unsigned pa = cvtpk(p[0], p[1]),   pb = cvtpk(p[2], p[3]);
    unsigned pc = cvtpk(p[4], p[5]),   pd = cvtpk(p[6], p[7]);
    unsigned pe = cvtpk(p[8], p[9]),   pf = cvtpk(p[10], p[11]);
    unsigned pg = cvtpk(p[12], p[13]), ph = cvtpk(p[14], p[15]);
    plswap(pa, pc);   // pa -> w0 (kv pair 0,1 / 8,9), pc -> w2
    plswap(pb, pd);   // pb -> w1, pd -> w3
    plswap(pe, pg);   // pe -> w4, pg -> w6
    plswap(pf, ph);   // pf -> w5, ph -> w7
    u32x4 A0 = {pa, pb, pc, pd};
    u32x4 A1 = {pe, pf, pg, ph};
    bf16x8 pA0 = __builtin_bit_cast(bf16x8, A0);
    bf16x8 pA1 = __builtin_bit_cast(bf16x8, A1);

    // PV: O[q][d] += P·V  (4 independent d-block chains)
    __builtin_amdgcn_s_setprio(1);
    #pragma unroll
    for (int d = 0; d < 4; ++d) {
      oac[d] = __builtin_amdgcn_mfma_f32_32x32x16_bf16(pA0, vfr[d], oac[d], 0, 0, 0);
      oac[d] = __builtin_amdgcn_mfma_f32_32x32x16_bf16(pA1, vfr[4 + d], oac[d], 0, 0, 0);
    }
    __builtin_amdgcn_s_setprio(0);
    __syncthreads();  // drains vmcnt -> K(i+1) staged; parity reuse safe
  }

  // ---- epilogue: partial O and l to workspace (no atomics) ----
  float lpart = lsum + __shfl(lsum, l ^ 32, 64);
  const int zk = z * 2 + ks;
  if (hi == 0)
    lbuf[(size_t)zk * (NB * NSEQ) + (size_t)b * NSEQ + q0w + lo] = lpart;
  float* ob = pbuf + ((size_t)zk * NB + b) * (NSEQ * DHEAD);
  #pragma unroll
  for (int d = 0; d < 4; ++d)
    #pragma unroll
    for (int r = 0; r < 16; ++r) {
      int row = (r & 3) + 8 * (r >> 2) + 4 * hi;
      ob[(size_t)(q0w + row) * DHEAD + d * 32 + lo] = oac[d][r];
    }
}

// ---------- finalize: out = 0.5*(sum_ks O_p0/l0 + sum_ks O_p1/l1) ----------
__global__ __launch_bounds__(256) void fin4(const float* __restrict__ pbuf,
                                            const float* __restrict__ lbuf,
                                            float* __restrict__ out) {
  const int idx = blockIdx.x * 256 + threadIdx.x;   // float4 unit, 524288 total
  const int row = idx >> 5, c4 = (idx & 31) * 4;
  const size_t R = (size_t)NB * NSEQ * DHEAD;
  const size_t o = (size_t)row * DHEAD + c4;
  float4 a0 = *(const float4*)(pbuf + o);
  float4 a1 = *(const float4*)(pbuf + R + o);
  float4 b0 = *(const float4*)(pbuf + 2 * R + o);
  float4 b1 = *(const float4*)(pbuf + 3 * R + o);
  float l0 = lbuf[row] + lbuf[16384 + row];
  float l1 = lbuf[2 * 16384 + row] + lbuf[3 * 16384 + row];
  float i0 = 0.5f / l0, i1 = 0.5f / l1;
  float4 r;
  r.x = (a0.x + a1.x) * i0 + (b0.x + b1.x) * i1;
  r.y = (a0.y + a1.y) * i0 + (b0.y + b1.y) * i1;
  r.z = (a0.z + a1.z) * i0 + (b0.z + b1.z) * i1;
  r.w = (a0.w + a1.w) * i0 + (b0.w + b1.w) * i1;
  *(float4*)(out + o) = r;
}

extern "C" void kernel_launch(void* const* d_in, const int* in_sizes, int n_in,
                              void* d_out, int out_size, void* d_ws, size_t ws_size,
                              hipStream_t stream) {
  const float* S = (const float*)d_in[0];
  const float* G = (const float*)d_in[1];
  unsigned short* ws = (unsigned short*)d_ws;
  float* pbuf = (float*)((char*)d_ws + PBUF_OFF);
  float* lbuf = (float*)((char*)d_ws + LBUF_OFF);
  float* outp = (float*)d_out;
  prep4<<<dim3(128, 4, 2), 256, 0, stream>>>(S, G, ws);
  xattn4<<<dim3(64, 4, 2), 256, 0, stream>>>(S, G, ws, pbuf, lbuf);
  fin4<<<2048, 256, 0, stream>>>(pbuf, lbuf, outp);
}